// Round 8
// baseline (161.504 us; speedup 1.0000x reference)
//
#include <hip/hip_runtime.h>

#define NROIS 512
#define NEDGES 262144

// ---------------------------------------------------------------------------
// edge_index may arrive as int64 (reference dtype) or int32 (harness downcast).
__device__ __forceinline__ int detect_i64(const unsigned* __restrict__ er) {
    unsigned acc = 0;
#pragma unroll
    for (int i = 0; i < 64; ++i) acc |= er[2 * i + 1];
    return acc == 0u;
}

__device__ __forceinline__ void load_edge(const unsigned* __restrict__ er,
                                          bool i64, int e, int& src, int& dst) {
    if (i64) { src = (int)er[2 * e]; dst = (int)er[2 * NEDGES + 2 * e]; }
    else     { src = (int)er[e];     dst = (int)er[NEDGES + e]; }
}

// ---------------------------------------------------------------------------
// hist: 64 blocks x 4096 edges, per-block LDS hist -> gpart[64][512]
__global__ __launch_bounds__(256) void hist_kernel(const unsigned* __restrict__ er,
                                                   int* __restrict__ gpart)
{
    __shared__ int lh[NROIS];
    __shared__ int s_l;
    const int t = threadIdx.x;
    if (t == 0) s_l = detect_i64(er);
    for (int i = t; i < NROIS; i += 256) lh[i] = 0;
    __syncthreads();
    const bool L = (s_l != 0);
    const int e0 = blockIdx.x * 4096;
#pragma unroll
    for (int k = 0; k < 16; ++k) {
        int e = e0 + k * 256 + t, src, dst;
        load_edge(er, L, e, src, dst);
        atomicAdd(&lh[dst], 1);
    }
    __syncthreads();
    for (int i = t; i < NROIS; i += 256) gpart[blockIdx.x * NROIS + i] = lh[i];
}

// scan: sum 64 partials per bin, inclusive scan -> start[513], cursor (exclusive)
__global__ __launch_bounds__(512) void scan_kernel(const int* __restrict__ gpart,
                                                   int* __restrict__ start,
                                                   int* __restrict__ cursor)
{
    __shared__ int tmp[NROIS];
    const int t = threadIdx.x;
    int own = 0;
#pragma unroll 8
    for (int b = 0; b < 64; ++b) own += gpart[b * NROIS + t];
    tmp[t] = own;
    __syncthreads();
    for (int off = 1; off < NROIS; off <<= 1) {
        int v = tmp[t];
        int add = (t >= off) ? tmp[t - off] : 0;
        __syncthreads();
        tmp[t] = v + add;
        __syncthreads();
    }
    start[t + 1] = tmp[t];
    if (t == 0) start[0] = 0;
    cursor[t] = tmp[t] - own;            // exclusive prefix
}

// scatter + fused pack: 256 blocks x 1024 edges. Per-block LDS bucketing, one
// global atomic per (block,bin). packed: eas rows only; else perm.
__global__ __launch_bounds__(256) void scatter_kernel(const unsigned* __restrict__ er,
                                                      const float* __restrict__ ea,
                                                      int* __restrict__ gcursor,
                                                      unsigned* __restrict__ perm,
                                                      float* __restrict__ eas,
                                                      int packed)
{
    __shared__ int lh[NROIS];
    __shared__ int lbase[NROIS];
    __shared__ int s_l;
    const int t = threadIdx.x;
    if (t == 0) s_l = detect_i64(er);
    for (int i = t; i < NROIS; i += 256) lh[i] = 0;
    __syncthreads();
    const bool L = (s_l != 0);
    const int e0 = blockIdx.x * 1024;
#pragma unroll
    for (int k = 0; k < 4; ++k) {
        int e = e0 + k * 256 + t, src, dst;
        load_edge(er, L, e, src, dst);
        atomicAdd(&lh[dst], 1);
    }
    __syncthreads();
    for (int i = t; i < NROIS; i += 256) {
        int c = lh[i];
        lbase[i] = c ? atomicAdd(&gcursor[i], c) : 0;
    }
    __syncthreads();
#pragma unroll
    for (int k = 0; k < 4; ++k) {
        int e = e0 + k * 256 + t, src, dst;
        load_edge(er, L, e, src, dst);
        int pos = atomicAdd(&lbase[dst], 1);
        unsigned ps = ((unsigned)e << 9) | (unsigned)src;
        if (packed) {
            const float2* s = reinterpret_cast<const float2*>(ea + (size_t)e * 6);
            const float2 a0 = s[0], a1 = s[1], a2 = s[2];
            float4* d = reinterpret_cast<float4*>(eas + (size_t)pos * 8);
            d[0] = make_float4(a0.x, a0.y, a1.x, a1.y);
            d[1] = make_float4(a2.x, a2.y, __uint_as_float(ps), 0.f);
        } else {
            perm[pos] = ps;
        }
    }
}

// ---------------------------------------------------------------------------
// Fused NNConv layer: block per dst; LANE OWNS AN EDGE. Weights are accessed
// with wave-uniform indices -> compiler emits s_load + SGPR-operand v_fma
// (zero VGPR cost, scalar pipe; rounds 4-7 proved per-lane weight arrays get
// remat'd/spilled). h_in staged in LDS with odd stride (conflict-free random
// row gather). Epilogue: shfl butterfly + LDS combine + fused node update.
template <int CIN, int COUT, int STR, bool PACKED>
__global__ __launch_bounds__(256) void layer_kernel(
    const float* __restrict__ eas, const float* __restrict__ ea,
    const unsigned* __restrict__ perm, const int* __restrict__ start,
    const float* __restrict__ lw, const float* __restrict__ lb,
    const float* __restrict__ root, const float* __restrict__ bias,
    const float* __restrict__ hin, float* __restrict__ hout)
{
    __shared__ float sh[NROIS * STR];
    __shared__ float red[4 * COUT];
    const int t = threadIdx.x;

    // stage h_in [NROIS][CIN] -> sh [NROIS][STR] (coalesced global reads)
    for (int idx = t; idx < NROIS * CIN; idx += 256) {
        const int r = idx / CIN;
        sh[r * STR + (idx - r * CIN)] = hin[idx];
    }
    __syncthreads();

    const int dst = blockIdx.x;
    const int s0 = start[dst], c1 = start[dst + 1];
    const int cnt = c1 - s0;

    float acc[COUT];
#pragma unroll
    for (int o = 0; o < COUT; ++o) acc[o] = 0.f;

    for (int idx = s0 + t; idx < c1; idx += 256) {
        float a0, a1, a2, a3, a4, a5;
        unsigned ps;
        if constexpr (PACKED) {
            const float4* __restrict__ base = reinterpret_cast<const float4*>(eas);
            const float4 r0 = base[2 * idx], r1 = base[2 * idx + 1];
            a0 = r0.x; a1 = r0.y; a2 = r0.z; a3 = r0.w;
            a4 = r1.x; a5 = r1.y; ps = __float_as_uint(r1.z);
        } else {
            ps = perm[idx];
            const float* __restrict__ ap = ea + (size_t)(ps >> 9) * 6;
            a0 = ap[0]; a1 = ap[1]; a2 = ap[2]; a3 = ap[3]; a4 = ap[4]; a5 = ap[5];
        }
        const int hbase = (int)(ps & 511u) * STR;

#pragma unroll 2
        for (int i = 0; i < CIN; ++i) {
            const float hsv = sh[hbase + i];
#pragma unroll
            for (int o = 0; o < COUT; ++o) {
                // all weight indices wave-uniform -> s_load / SGPR operands
                float tt = lb[i * COUT + o];
                tt = fmaf(a0, lw[0 * (CIN * COUT) + i * COUT + o], tt);
                tt = fmaf(a1, lw[1 * (CIN * COUT) + i * COUT + o], tt);
                tt = fmaf(a2, lw[2 * (CIN * COUT) + i * COUT + o], tt);
                tt = fmaf(a3, lw[3 * (CIN * COUT) + i * COUT + o], tt);
                tt = fmaf(a4, lw[4 * (CIN * COUT) + i * COUT + o], tt);
                tt = fmaf(a5, lw[5 * (CIN * COUT) + i * COUT + o], tt);
                acc[o] = fmaf(hsv, fmaxf(tt, 0.f), acc[o]);
            }
        }
    }

    // 64-lane butterfly reduce, then combine 4 waves via LDS
#pragma unroll
    for (int o = 0; o < COUT; ++o) {
        float v = acc[o];
#pragma unroll
        for (int d = 32; d > 0; d >>= 1) v += __shfl_xor(v, d);
        acc[o] = v;
    }
    const int lane = t & 63, wid = t >> 6;
    if (lane == 0) {
#pragma unroll
        for (int o = 0; o < COUT; ++o) red[wid * COUT + o] = acc[o];
    }
    __syncthreads();

    // fused node update: mean + root term + bias + relu
    if (t < COUT) {
        float tot = red[t] + red[COUT + t] + red[2 * COUT + t] + red[3 * COUT + t];
        float aggr = tot / fmaxf((float)cnt, 1.f);
        float r = bias[t];
#pragma unroll 4
        for (int k = 0; k < CIN; ++k)
            r = fmaf(sh[dst * STR + k], root[k * COUT + t], r);
        hout[dst * COUT + t] = fmaxf(aggr + r, 0.f);
    }
}

// cbt[i,j] = sum_k |h[i,k]-h[j,k]|, h: [512,5] staged in LDS, block per row i
__global__ __launch_bounds__(256) void cbt_kernel(const float* __restrict__ h,
                                                  float* __restrict__ out)
{
    __shared__ float sh[NROIS * 5];
    for (int t = threadIdx.x; t < NROIS * 5; t += 256) sh[t] = h[t];
    __syncthreads();
    const int i = blockIdx.x;
    float hi[5];
#pragma unroll
    for (int k = 0; k < 5; ++k) hi[k] = sh[i * 5 + k];
    for (int j = threadIdx.x; j < NROIS; j += 256) {
        float s = 0.f;
#pragma unroll
        for (int k = 0; k < 5; ++k) s += fabsf(hi[k] - sh[j * 5 + k]);
        out[i * NROIS + j] = s;
    }
}

// ---------------------------------------------------------------------------
template <bool PACKED>
static void run_layers(const float* x, const float* ea,
                       const float* lw1, const float* lb1, const float* root1, const float* b1,
                       const float* lw2, const float* lb2, const float* root2, const float* b2,
                       const float* lw3, const float* lb3, const float* root3, const float* b3,
                       const float* eas, const unsigned* perm, const int* start,
                       float* h1, float* h2, float* h3, hipStream_t stream)
{
    layer_kernel<1, 36, 1, PACKED><<<NROIS, 256, 0, stream>>>(
        eas, ea, perm, start, lw1, lb1, root1, b1, x, h1);
    layer_kernel<36, 24, 37, PACKED><<<NROIS, 256, 0, stream>>>(
        eas, ea, perm, start, lw2, lb2, root2, b2, h1, h2);
    layer_kernel<24, 5, 25, PACKED><<<NROIS, 256, 0, stream>>>(
        eas, ea, perm, start, lw3, lb3, root3, b3, h2, h3);
}

extern "C" void kernel_launch(void* const* d_in, const int* in_sizes, int n_in,
                              void* d_out, int out_size, void* d_ws, size_t ws_size,
                              hipStream_t stream)
{
    const float*    x     = (const float*)d_in[0];
    const float*    ea    = (const float*)d_in[1];
    const unsigned* er    = (const unsigned*)d_in[2];
    const float*    lw1   = (const float*)d_in[3];
    const float*    lb1   = (const float*)d_in[4];
    const float*    root1 = (const float*)d_in[5];
    const float*    b1    = (const float*)d_in[6];
    const float*    lw2   = (const float*)d_in[7];
    const float*    lb2   = (const float*)d_in[8];
    const float*    root2 = (const float*)d_in[9];
    const float*    b2    = (const float*)d_in[10];
    const float*    lw3   = (const float*)d_in[11];
    const float*    lb3   = (const float*)d_in[12];
    const float*    root3 = (const float*)d_in[13];
    const float*    b3    = (const float*)d_in[14];

    const size_t easN  = (size_t)NEDGES * 8;                 // floats
    const size_t restN = 18432 + 12288 + 2560 + 131072 + 513 + 512 + NEDGES;
    const size_t needPacked = (easN + restN) * 4;
    const int packed = (ws_size >= needPacked) ? 1 : 0;

    float* ws   = (float*)d_ws;
    float* eas  = ws;                                  // 8 MB (packed mode only)
    float* rest = packed ? (ws + easN) : ws;
    float* h1   = rest;                 // 512*36
    float* h2   = h1 + NROIS * 36;      // 512*24
    float* h3   = h2 + NROIS * 24;      // 512*5
    int* gpart  = (int*)(h3 + NROIS * 5);   // 64*512 ints, pre-layer only
    int* start  = gpart + 131072;
    int* cursor = start + NROIS + 1;    // 512
    unsigned* perm = (unsigned*)(cursor + NROIS);      // 262144

    // --- counting sort by dst + fused edge-attr pack (reused by all layers) ---
    hist_kernel<<<NEDGES / 4096, 256, 0, stream>>>(er, gpart);
    scan_kernel<<<1, 512, 0, stream>>>(gpart, start, cursor);
    scatter_kernel<<<NEDGES / 1024, 256, 0, stream>>>(er, ea, cursor, perm, eas, packed);

    if (packed)
        run_layers<true>(x, ea, lw1, lb1, root1, b1, lw2, lb2, root2, b2,
                         lw3, lb3, root3, b3, eas, perm, start, h1, h2, h3, stream);
    else
        run_layers<false>(x, ea, lw1, lb1, root1, b1, lw2, lb2, root2, b2,
                          lw3, lb3, root3, b3, eas, perm, start, h1, h2, h3, stream);

    // --- pairwise L1 distance tail ---
    cbt_kernel<<<NROIS, 256, 0, stream>>>(h3, (float*)d_out);
}